// Round 1
// baseline (1085.744 us; speedup 1.0000x reference)
//
#include <hip/hip_runtime.h>
#include <hip/hip_bf16.h>

// Problem constants
#define V 512
#define H 8
#define D 64
#define L 16
#define B 4096
#define F1 64
#define F2 64
#define F3 8

// ---------------------------------------------------------------------------
// Kernel A: qkv = emb0 @ w_qkv   (emb row 0 forced to zero)
// qkv layout: [v][24*64] where cols 0..511=q, 512..1023=k, 1024..1535=v
// grid (6, 8): 6 col-blocks of 256, 8 v-blocks of 64
// ---------------------------------------------------------------------------
__global__ __launch_bounds__(256) void qkv_kernel(const float* __restrict__ emb,
                                                  const float* __restrict__ w_qkv,
                                                  float* __restrict__ qkv)
{
    const int c = blockIdx.x * 256 + threadIdx.x;   // 0..1535
    const int vbase = blockIdx.y * 64;
    float wcol[64];
#pragma unroll
    for (int k = 0; k < 64; ++k) wcol[k] = w_qkv[k * 1536 + c];
    for (int v = vbase; v < vbase + 64; ++v) {
        if (v == 0) { qkv[c] = 0.0f; continue; }   // emb.at[0].set(0)
        float acc = 0.0f;
#pragma unroll
        for (int k = 0; k < 64; ++k) acc = fmaf(emb[v * 64 + k], wcol[k], acc);
        qkv[v * 1536 + c] = acc;
    }
}

// ---------------------------------------------------------------------------
// Kernel B: sim[qi][h][kj] = dot(q[qi,h,:], k[kj,h,:]) / 8 ;  sim[*][*][0]=-1e9
// grid (8 qi-tiles, 8 kj-tiles, 8 heads), block 256
// ---------------------------------------------------------------------------
__global__ __launch_bounds__(256) void sim_kernel(const float* __restrict__ qkv,
                                                  float* __restrict__ sim)
{
    __shared__ float qt[64 * 65];
    __shared__ float kt[64 * 65];
    const int t = threadIdx.x;
    const int qb = blockIdx.x, kb = blockIdx.y, h = blockIdx.z;
#pragma unroll
    for (int n = 0; n < 16; ++n) {
        int o = n * 256 + t;            // 0..4095
        int r = o >> 6, dd = o & 63;
        qt[r * 65 + dd] = qkv[(qb * 64 + r) * 1536 + h * 64 + dd];
        kt[r * 65 + dd] = qkv[(kb * 64 + r) * 1536 + 512 + h * 64 + dd];
    }
    __syncthreads();
    const int kj = t & 63, r0 = t >> 6;
    for (int ii = 0; ii < 16; ++ii) {
        const int qr = r0 * 16 + ii;
        float acc = 0.0f;
#pragma unroll
        for (int dd = 0; dd < 64; ++dd)
            acc = fmaf(qt[qr * 65 + dd], kt[kj * 65 + dd], acc);
        const int kglob = kb * 64 + kj;
        float val = acc * 0.125f;       // / sqrt(64)
        if (kglob == 0) val = -1.0e9f;
        sim[((qb * 64 + qr) * 8 + h) * 512 + kglob] = val;
    }
}

// ---------------------------------------------------------------------------
// Kernel C: per-b attention gather + softmax + PV + LayerNorm + MLP + masked sum
// one block per b; 256 threads (4 waves)
// LDS: tokS(64B) + scratch(24KB: p[16][128] | v[16][4][64]; part overlays)
//      + xS 16*64*9 f32 (36KB)  -> 61.5KB total, 2 blocks/CU
// ---------------------------------------------------------------------------
__global__ __launch_bounds__(256, 2) void main_kernel(
    const int* __restrict__ inputs,
    const float* __restrict__ qkv, const float* __restrict__ sim,
    const float* __restrict__ gamma, const float* __restrict__ beta,
    const float* __restrict__ w1, const float* __restrict__ b1,
    const float* __restrict__ w2, const float* __restrict__ b2,
    const float* __restrict__ w3, const float* __restrict__ b3,
    float* __restrict__ wft)
{
    __shared__ int   tokS[16];
    __shared__ float scratch[6144];  // [0,2048): p as [j][128] ; [2048,6144): v as [j][4][64]
    __shared__ float xS[16 * 576];   // x[i][d][h] padded inner dim 9

    const int t = threadIdx.x;
    const int b = blockIdx.x;
    const int lane = t & 63;
    const int w = t >> 6;

    if (t < 16) tokS[t] = inputs[b * 16 + t];
    __syncthreads();

    int cnt = 0;
#pragma unroll
    for (int j2 = 0; j2 < 16; ++j2) cnt += (tokS[j2] != 0) ? 1 : 0;
    const float inv_msum = 1.0f / (float)cnt;

    const float gamv = gamma[lane];
    const float betv = beta[lane];

    // phase 1: gather raw scores into p[j][r], r = i*8+h; stage v for heads 0..3
#pragma unroll
    for (int n = 0; n < 8; ++n) {
        int o = n * 256 + t;            // 0..2047
        int j = o >> 7, r = o & 127;
        int i = r >> 3, h = r & 7;
        scratch[o] = sim[(tokS[i] * 8 + h) * 512 + tokS[j]];
    }
#pragma unroll
    for (int n = 0; n < 16; ++n) {
        int o = n * 256 + t;            // 0..4095
        int j = o >> 8, hh = (o >> 6) & 3, d = o & 63;
        scratch[2048 + o] = qkv[tokS[j] * 1536 + 1024 + hh * 64 + d];
    }
    __syncthreads();

    // phase 2: softmax over j for each of 128 rows
    if (t < 128) {
        float s[16];
        float m = -3.0e38f;
#pragma unroll
        for (int j = 0; j < 16; ++j) { s[j] = scratch[j * 128 + t]; m = fmaxf(m, s[j]); }
        float sum = 0.0f;
#pragma unroll
        for (int j = 0; j < 16; ++j) { s[j] = __expf(s[j] - m); sum += s[j]; }
        float inv = 1.0f / sum;
#pragma unroll
        for (int j = 0; j < 16; ++j) scratch[j * 128 + t] = s[j] * inv;
    }
    __syncthreads();

    // phases 3-5: PV + LayerNorm, heads in two halves (v staged 16KB at a time)
    for (int half = 0; half < 2; ++half) {
        if (half == 1) {
            __syncthreads();            // prior PV reads done before re-stage
#pragma unroll
            for (int n = 0; n < 16; ++n) {
                int o = n * 256 + t;
                int j = o >> 8, hh = (o >> 6) & 3, d = o & 63;
                scratch[2048 + o] = qkv[tokS[j] * 1536 + 1024 + (4 + hh) * 64 + d];
            }
            __syncthreads();
        }
        const int hbase = half * 4;
        for (int n = 0; n < 16; ++n) {
            int r = w * 16 + n;         // 0..63
            int i = r >> 2, hh = r & 3;
            int h = hbase + hh;
            float acc = 0.0f;
#pragma unroll
            for (int j = 0; j < 16; ++j)
                acc = fmaf(scratch[j * 128 + (i * 8 + h)],
                           scratch[2048 + (j * 4 + hh) * 64 + lane], acc);
            // LayerNorm across the 64 lanes (d dimension)
            float ssum = acc;
#pragma unroll
            for (int off = 32; off > 0; off >>= 1) ssum += __shfl_xor(ssum, off);
            float mu = ssum * (1.0f / 64.0f);
            float dfx = acc - mu;
            float vsum = dfx * dfx;
#pragma unroll
            for (int off = 32; off > 0; off >>= 1) vsum += __shfl_xor(vsum, off);
            float var = vsum * (1.0f / 64.0f);
            float y = dfx / sqrtf(var + 1e-6f) * gamv + betv;
            xS[i * 576 + lane * 9 + h] = y;
        }
    }
    __syncthreads();

    // phase 6: MLP per (i,d) row; lane=d, wave w handles i = w*4..w*4+3
    float wacc[8];
#pragma unroll
    for (int c = 0; c < 8; ++c) wacc[c] = 0.0f;
    const int d = lane;
    for (int n = 0; n < 4; ++n) {
        const int i = w * 4 + n;
        if (tokS[i] == 0) continue;     // masked position: zero contribution
        float x8[8];
#pragma unroll
        for (int hh = 0; hh < 8; ++hh) x8[hh] = xS[i * 576 + d * 9 + hh];
        float h1v[64];
#pragma unroll
        for (int f = 0; f < 64; ++f) h1v[f] = b1[f];
#pragma unroll
        for (int hh = 0; hh < 8; ++hh) {
            const float xv = x8[hh];
#pragma unroll
            for (int f = 0; f < 64; ++f) h1v[f] = fmaf(xv, w1[hh * 64 + f], h1v[f]);
        }
#pragma unroll
        for (int f = 0; f < 64; ++f) h1v[f] = fmaxf(h1v[f], 0.0f);
        float h3v[8];
#pragma unroll
        for (int c = 0; c < 8; ++c) h3v[c] = b3[c];
        for (int gb = 0; gb < 2; ++gb) {        // runtime loop: keeps I-footprint small
            const int goff = gb * 32;
            float a2[32];
#pragma unroll
            for (int g = 0; g < 32; ++g) a2[g] = b2[goff + g];
#pragma unroll
            for (int f = 0; f < 64; ++f) {
                const float hf = h1v[f];
#pragma unroll
                for (int g = 0; g < 32; ++g)
                    a2[g] = fmaf(hf, w2[f * 64 + goff + g], a2[g]);
            }
#pragma unroll
            for (int g = 0; g < 32; ++g) {
                const float rg = fmaxf(a2[g], 0.0f);
#pragma unroll
                for (int c = 0; c < 8; ++c)
                    h3v[c] = fmaf(rg, w3[(goff + g) * 8 + c], h3v[c]);
            }
        }
#pragma unroll
        for (int c = 0; c < 8; ++c) wacc[c] += h3v[c];
    }
    // partial sums: part[w][d][c] overlays scratch (p/v dead now)
#pragma unroll
    for (int c = 0; c < 8; ++c) scratch[w * 576 + d * 9 + c] = wacc[c];
    __syncthreads();

    // phase 7: reduce 4 waves, scale by 1/mask_sum, write word features
#pragma unroll
    for (int rep = 0; rep < 2; ++rep) {
        int f = rep * 256 + t;          // 0..511
        int dd = f >> 3, c = f & 7;
        float s4 = 0.0f;
#pragma unroll
        for (int ww = 0; ww < 4; ++ww) s4 += scratch[ww * 576 + dd * 9 + c];
        wft[b * 512 + f] = s4 * inv_msum;
    }
}

// ---------------------------------------------------------------------------
// Kernel D: name_ft[g][f] = mean over 8 words of word_ft
// ---------------------------------------------------------------------------
__global__ __launch_bounds__(256) void reduce_kernel(const float* __restrict__ wft,
                                                     float* __restrict__ out)
{
    const int o = blockIdx.x * 256 + threadIdx.x;   // 0..262143
    const int g = o >> 9, f = o & 511;
    float s = 0.0f;
#pragma unroll
    for (int ww = 0; ww < 8; ++ww) s += wft[(g * 8 + ww) * 512 + f];
    out[o] = s * 0.125f;
}

// ---------------------------------------------------------------------------
extern "C" void kernel_launch(void* const* d_in, const int* in_sizes, int n_in,
                              void* d_out, int out_size, void* d_ws, size_t ws_size,
                              hipStream_t stream)
{
    const int*   inputs = (const int*)  d_in[0];
    const float* emb    = (const float*)d_in[1];
    const float* w_qkv  = (const float*)d_in[2];
    const float* gam    = (const float*)d_in[3];
    const float* bet    = (const float*)d_in[4];
    const float* w1     = (const float*)d_in[5];
    const float* b1     = (const float*)d_in[6];
    const float* w2     = (const float*)d_in[7];
    const float* b2     = (const float*)d_in[8];
    const float* w3     = (const float*)d_in[9];
    const float* b3     = (const float*)d_in[10];

    float* qkv = (float*)d_ws;                   // 512*1536 f32 = 3MB
    float* sim = qkv + 512 * 1536;               // 512*8*512 f32 = 8MB
    float* wft = sim + 512 * 8 * 512;            // 4096*512 f32 = 8MB
    float* out = (float*)d_out;

    qkv_kernel  <<<dim3(6, 8),    256, 0, stream>>>(emb, w_qkv, qkv);
    sim_kernel  <<<dim3(8, 8, 8), 256, 0, stream>>>(qkv, sim);
    main_kernel <<<4096,          256, 0, stream>>>(inputs, qkv, sim, gam, bet,
                                                    w1, b1, w2, b2, w3, b3, wft);
    reduce_kernel<<<1024,         256, 0, stream>>>(wft, out);
}

// Round 4
// 544.928 us; speedup vs baseline: 1.9925x; 1.9925x over previous
//
#include <hip/hip_runtime.h>
#include <hip/hip_bf16.h>
#include <stdint.h>

// Problem constants
#define V 512
#define H 8
#define D 64
#define L 16
#define B 4096

typedef __attribute__((ext_vector_type(8))) short short8;
typedef __attribute__((ext_vector_type(4))) float float4_t;

union Frag { uint32_t u[4]; short8 s; };

// split fp32 x into bf16 hi (truncated) + bf16 lo (residual, truncated).
// Represented value error ~2^-16 relative; dropped lo*lo term ~2^-16.
__device__ __forceinline__ void split_hl(float x, uint32_t& hi, uint32_t& lo) {
    uint32_t uu = __float_as_uint(x);
    hi = uu >> 16;
    float fl = x - __uint_as_float(uu & 0xffff0000u);
    lo = __float_as_uint(fl) >> 16;
}
// pack (hi16|lo16) into one u32
__device__ __forceinline__ uint32_t pack_hl(float x) {
    uint32_t uu = __float_as_uint(x);
    uint32_t ha = uu & 0xffff0000u;
    float fl = x - __uint_as_float(ha);
    return ha | (__float_as_uint(fl) >> 16);
}

// ---------------------------------------------------------------------------
// Kernel A: qkv = emb0 @ w_qkv   (emb row 0 forced to zero)
// ---------------------------------------------------------------------------
__global__ __launch_bounds__(256) void qkv_kernel(const float* __restrict__ emb,
                                                  const float* __restrict__ w_qkv,
                                                  float* __restrict__ qkv)
{
    const int c = blockIdx.x * 256 + threadIdx.x;   // 0..1535
    const int vbase = blockIdx.y * 64;
    float wcol[64];
#pragma unroll
    for (int k = 0; k < 64; ++k) wcol[k] = w_qkv[k * 1536 + c];
    for (int v = vbase; v < vbase + 64; ++v) {
        if (v == 0) { qkv[c] = 0.0f; continue; }
        float acc = 0.0f;
#pragma unroll
        for (int k = 0; k < 64; ++k) acc = fmaf(emb[v * 64 + k], wcol[k], acc);
        qkv[v * 1536 + c] = acc;
    }
}

// ---------------------------------------------------------------------------
// Kernel B: sim[qi][h][kj] = dot(q[qi,h,:], k[kj,h,:]) / 8 ; sim[*][*][0]=-1e9
// ---------------------------------------------------------------------------
__global__ __launch_bounds__(256) void sim_kernel(const float* __restrict__ qkv,
                                                  float* __restrict__ sim)
{
    __shared__ float qt[64 * 65];
    __shared__ float kt[64 * 65];
    const int t = threadIdx.x;
    const int qb = blockIdx.x, kb = blockIdx.y, h = blockIdx.z;
#pragma unroll
    for (int n = 0; n < 16; ++n) {
        int o = n * 256 + t;
        int r = o >> 6, dd = o & 63;
        qt[r * 65 + dd] = qkv[(qb * 64 + r) * 1536 + h * 64 + dd];
        kt[r * 65 + dd] = qkv[(kb * 64 + r) * 1536 + 512 + h * 64 + dd];
    }
    __syncthreads();
    const int kj = t & 63, r0 = t >> 6;
    for (int ii = 0; ii < 16; ++ii) {
        const int qr = r0 * 16 + ii;
        float acc = 0.0f;
#pragma unroll
        for (int dd = 0; dd < 64; ++dd)
            acc = fmaf(qt[qr * 65 + dd], kt[kj * 65 + dd], acc);
        const int kglob = kb * 64 + kj;
        float val = acc * 0.125f;
        if (kglob == 0) val = -1.0e9f;
        sim[((qb * 64 + qr) * 8 + h) * 512 + kglob] = val;
    }
}

// ---------------------------------------------------------------------------
// Kernel C: gather + softmax + PV + LayerNorm + split-bf16 MFMA MLP + pooling
// one block per b; 256 threads (4 waves), 2 blocks/CU (56.1 KB LDS)
// ---------------------------------------------------------------------------
__global__ __launch_bounds__(256, 2) void main_kernel(
    const int* __restrict__ inputs,
    const float* __restrict__ qkv, const float* __restrict__ sim,
    const float* __restrict__ gamma, const float* __restrict__ beta,
    const float* __restrict__ w1, const float* __restrict__ b1,
    const float* __restrict__ w2, const float* __restrict__ b2,
    const float* __restrict__ w3, const float* __restrict__ b3,
    float* __restrict__ wft)
{
    __shared__ int      tokS[16];
    __shared__ float    scratch[6144];   // p[0,2048) | v[2048,6144) ; phase6: per-wave h1buf
    __shared__ uint32_t xSu[16 * 8 * 64]; // x packed (bf16hi|bf16lo), [i][h][d]; later: partF

    const int t = threadIdx.x;
    const int b = blockIdx.x;
    const int lane = t & 63;
    const int w = t >> 6;

    if (t < 16) tokS[t] = inputs[b * 16 + t];
    __syncthreads();

    int cnt = 0;
#pragma unroll
    for (int j2 = 0; j2 < 16; ++j2) cnt += (tokS[j2] != 0) ? 1 : 0;
    const float inv_msum = 1.0f / (float)cnt;

    const float gamv = gamma[lane];
    const float betv = beta[lane];

    // phase 1: gather raw scores p[j][i*8+h]; stage v for heads 0..3
#pragma unroll
    for (int n = 0; n < 8; ++n) {
        int o = n * 256 + t;
        int j = o >> 7, r = o & 127;
        int i = r >> 3, h = r & 7;
        scratch[o] = sim[(tokS[i] * 8 + h) * 512 + tokS[j]];
    }
#pragma unroll
    for (int n = 0; n < 16; ++n) {
        int o = n * 256 + t;
        int j = o >> 8, hh = (o >> 6) & 3, d = o & 63;
        scratch[2048 + o] = qkv[tokS[j] * 1536 + 1024 + hh * 64 + d];
    }
    __syncthreads();

    // phase 2: softmax over j for each of 128 (i,h) rows
    if (t < 128) {
        float s[16];
        float m = -3.0e38f;
#pragma unroll
        for (int j = 0; j < 16; ++j) { s[j] = scratch[j * 128 + t]; m = fmaxf(m, s[j]); }
        float sum = 0.0f;
#pragma unroll
        for (int j = 0; j < 16; ++j) { s[j] = __expf(s[j] - m); sum += s[j]; }
        float inv = 1.0f / sum;
#pragma unroll
        for (int j = 0; j < 16; ++j) scratch[j * 128 + t] = s[j] * inv;
    }
    __syncthreads();

    // phases 3-5: PV + LayerNorm; write packed hi|lo x to xSu[i][h][d]
    for (int half = 0; half < 2; ++half) {
        if (half == 1) {
            __syncthreads();
#pragma unroll
            for (int n = 0; n < 16; ++n) {
                int o = n * 256 + t;
                int j = o >> 8, hh = (o >> 6) & 3, d = o & 63;
                scratch[2048 + o] = qkv[tokS[j] * 1536 + 1024 + (4 + hh) * 64 + d];
            }
            __syncthreads();
        }
        const int hbase = half * 4;
        for (int n = 0; n < 16; ++n) {
            int r = w * 16 + n;         // 0..63 = (i, hh)
            int i = r >> 2, hh = r & 3;
            int h = hbase + hh;
            float acc = 0.0f;
#pragma unroll
            for (int j = 0; j < 16; ++j)
                acc = fmaf(scratch[j * 128 + (i * 8 + h)],
                           scratch[2048 + (j * 4 + hh) * 64 + lane], acc);
            float ssum = acc;
#pragma unroll
            for (int off = 32; off > 0; off >>= 1) ssum += __shfl_xor(ssum, off);
            float mu = ssum * (1.0f / 64.0f);
            float dfx = acc - mu;
            float vsum = dfx * dfx;
#pragma unroll
            for (int off = 32; off > 0; off >>= 1) vsum += __shfl_xor(vsum, off);
            float var = vsum * (1.0f / 64.0f);
            float y = dfx / sqrtf(var + 1e-6f) * gamv + betv;
            xSu[i * 512 + h * 64 + lane] = pack_hl(y);   // conflict-free (lane=d)
        }
    }
    __syncthreads();

    // ---- phase 6: MLP via split-bf16 MFMA (transposed: h^T = W^T @ x^T) ----
    const int lq = lane >> 4;           // operand k-quadrant
    const int ln = lane & 15;           // M row (weights) / N col (row-id)
    uint32_t* h1buf = reinterpret_cast<uint32_t*>(scratch) + w * 1024; // 4KB/wave, p+v dead

    // --- weight fragments (once per wave) ---
    Frag a1[4];                  // w1^T K-packed split: q0 hi | q1 lo | q2 hi | q3 0
    Frag a2h[4][2], a2l[4][2];   // w2^T hi/lo per (mt, kstep)
    Frag a3h[2], a3l[2];         // w3^T (rows 8..15 zero)
    float b1v[4][4], b2v[4][4], b3v[4];

#pragma unroll
    for (int mt = 0; mt < 4; ++mt) {
        const int fout = mt * 16 + ln;
#pragma unroll
        for (int j = 0; j < 4; ++j) {
            uint32_t h0, l0, h1_, l1_;
            split_hl(w1[(2 * j) * 64 + fout], h0, l0);
            split_hl(w1[(2 * j + 1) * 64 + fout], h1_, l1_);
            uint32_t hw = h0 | (h1_ << 16);
            uint32_t lw = l0 | (l1_ << 16);
            a1[mt].u[j] = (lq == 3) ? 0u : ((lq == 1) ? lw : hw);
        }
#pragma unroll
        for (int r = 0; r < 4; ++r) {
            b1v[mt][r] = b1[mt * 16 + lq * 4 + r];
            b2v[mt][r] = b2[mt * 16 + lq * 4 + r];
        }
    }
#pragma unroll
    for (int mt = 0; mt < 4; ++mt)
#pragma unroll
        for (int s = 0; s < 2; ++s)
#pragma unroll
            for (int j = 0; j < 4; ++j) {
                const int fout = mt * 16 + ln;
                const int fin0 = s * 32 + lq * 8 + 2 * j;
                uint32_t h0, l0, h1_, l1_;
                split_hl(w2[fin0 * 64 + fout], h0, l0);
                split_hl(w2[(fin0 + 1) * 64 + fout], h1_, l1_);
                a2h[mt][s].u[j] = h0 | (h1_ << 16);
                a2l[mt][s].u[j] = l0 | (l1_ << 16);
            }
#pragma unroll
    for (int s = 0; s < 2; ++s)
#pragma unroll
        for (int j = 0; j < 4; ++j) {
            const int fin0 = s * 32 + lq * 8 + 2 * j;
            float v0 = (ln < 8) ? w3[fin0 * 8 + ln] : 0.0f;
            float v1 = (ln < 8) ? w3[(fin0 + 1) * 8 + ln] : 0.0f;
            uint32_t h0, l0, h1_, l1_;
            split_hl(v0, h0, l0);
            split_hl(v1, h1_, l1_);
            a3h[s].u[j] = h0 | (h1_ << 16);
            a3l[s].u[j] = l0 | (l1_ << 16);
        }
#pragma unroll
    for (int r = 0; r < 4; ++r) b3v[r] = b3[(lq & 1) * 4 + r];  // only lq<2 used

    float wacc[4][4];
#pragma unroll
    for (int dc = 0; dc < 4; ++dc)
#pragma unroll
        for (int r = 0; r < 4; ++r) wacc[dc][r] = 0.0f;

    const float4_t zf = {0.0f, 0.0f, 0.0f, 0.0f};

#pragma unroll 1
    for (int n6 = 0; n6 < 4; ++n6) {
        const int i = w * 4 + n6;
        if (tokS[i] == 0) continue;     // masked char: zero contribution
#pragma unroll
        for (int dc = 0; dc < 4; ++dc) {
            // B1: x-rows (i, d=dc*16+ln); k-pack q0 hi | q1 hi | q2 lo | q3 0
            uint32_t r8[8];
            const int xb = i * 512 + dc * 16 + ln;
#pragma unroll
            for (int h = 0; h < 8; ++h) r8[h] = xSu[xb + h * 64];
            Frag B1;
#pragma unroll
            for (int j = 0; j < 4; ++j) {
                uint32_t hd = (r8[2 * j] >> 16) | (r8[2 * j + 1] & 0xffff0000u);
                uint32_t ld = (r8[2 * j] & 0xffffu) | (r8[2 * j + 1] << 16);
                B1.u[j] = (lq == 3) ? 0u : ((lq == 2) ? ld : hd);
            }
            float4_t acc[4];
#pragma unroll
            for (int mt = 0; mt < 4; ++mt)
                acc[mt] = __builtin_amdgcn_mfma_f32_16x16x32_bf16(a1[mt].s, B1.s, zf, 0, 0, 0);
            // h1 = relu(acc+b1) -> split-pack -> h1buf[f][ln ^ ((f>>2)&3)]
#pragma unroll
            for (int mt = 0; mt < 4; ++mt)
#pragma unroll
                for (int r = 0; r < 4; ++r) {
                    float v = fmaxf(acc[mt][r] + b1v[mt][r], 0.0f);
                    int f = mt * 16 + lq * 4 + r;       // (f>>2)&3 == lq here
                    h1buf[f * 16 + (ln ^ lq)] = pack_hl(v);
                }
            // B2 frags from h1buf
            Frag B2h[2], B2l[2];
#pragma unroll
            for (int s = 0; s < 2; ++s) {
                uint32_t q8[8];
#pragma unroll
                for (int e = 0; e < 8; ++e) {
                    int f = s * 32 + lq * 8 + e;
                    q8[e] = h1buf[f * 16 + (ln ^ ((f >> 2) & 3))];
                }
#pragma unroll
                for (int j = 0; j < 4; ++j) {
                    B2h[s].u[j] = (q8[2 * j] >> 16) | (q8[2 * j + 1] & 0xffff0000u);
                    B2l[s].u[j] = (q8[2 * j] & 0xffffu) | (q8[2 * j + 1] << 16);
                }
            }
#pragma unroll
            for (int mt = 0; mt < 4; ++mt) {
                float4_t a = zf;
#pragma unroll
                for (int s = 0; s < 2; ++s) {
                    a = __builtin_amdgcn_mfma_f32_16x16x32_bf16(a2h[mt][s].s, B2h[s].s, a, 0, 0, 0);
                    a = __builtin_amdgcn_mfma_f32_16x16x32_bf16(a2l[mt][s].s, B2h[s].s, a, 0, 0, 0);
                    a = __builtin_amdgcn_mfma_f32_16x16x32_bf16(a2h[mt][s].s, B2l[s].s, a, 0, 0, 0);
                }
                acc[mt] = a;
            }
            // h2 -> h1buf (in-order LDS per wave: prior reads complete first)
#pragma unroll
            for (int mt = 0; mt < 4; ++mt)
#pragma unroll
                for (int r = 0; r < 4; ++r) {
                    float v = fmaxf(acc[mt][r] + b2v[mt][r], 0.0f);
                    int f = mt * 16 + lq * 4 + r;
                    h1buf[f * 16 + (ln ^ lq)] = pack_hl(v);
                }
            // B3 + S3 (single m-tile, rows 8..15 of A are zero)
            float4_t a3 = zf;
#pragma unroll
            for (int s = 0; s < 2; ++s) {
                uint32_t q8[8];
#pragma unroll
                for (int e = 0; e < 8; ++e) {
                    int f = s * 32 + lq * 8 + e;
                    q8[e] = h1buf[f * 16 + (ln ^ ((f >> 2) & 3))];
                }
                Frag Bh, Bl;
#pragma unroll
                for (int j = 0; j < 4; ++j) {
                    Bh.u[j] = (q8[2 * j] >> 16) | (q8[2 * j + 1] & 0xffff0000u);
                    Bl.u[j] = (q8[2 * j] & 0xffffu) | (q8[2 * j + 1] << 16);
                }
                a3 = __builtin_amdgcn_mfma_f32_16x16x32_bf16(a3h[s].s, Bh.s, a3, 0, 0, 0);
                a3 = __builtin_amdgcn_mfma_f32_16x16x32_bf16(a3l[s].s, Bh.s, a3, 0, 0, 0);
                a3 = __builtin_amdgcn_mfma_f32_16x16x32_bf16(a3h[s].s, Bl.s, a3, 0, 0, 0);
            }
#pragma unroll
            for (int r = 0; r < 4; ++r) wacc[dc][r] += a3[r] + b3v[r];
        }
    }

    // phase 7: cross-wave reduce; partF overlays xSu (all reads done)
    __syncthreads();
    float* partF = reinterpret_cast<float*>(xSu);   // [w][c][d] = [4][8][64]
    if (lq < 2) {
#pragma unroll
        for (int dc = 0; dc < 4; ++dc)
#pragma unroll
            for (int r = 0; r < 4; ++r)
                partF[w * 512 + (lq * 4 + r) * 64 + dc * 16 + ln] = wacc[dc][r];
    }
    __syncthreads();
#pragma unroll
    for (int rep = 0; rep < 2; ++rep) {
        int f = rep * 256 + t;          // 0..511 ; f = d*8 + c
        int dd = f >> 3, c = f & 7;
        float s4 = 0.0f;
#pragma unroll
        for (int ww = 0; ww < 4; ++ww) s4 += partF[ww * 512 + c * 64 + dd];
        wft[b * 512 + f] = s4 * inv_msum;
    }
}

// ---------------------------------------------------------------------------
// Kernel D: name_ft = mean over 8 words
// ---------------------------------------------------------------------------
__global__ __launch_bounds__(256) void reduce_kernel(const float* __restrict__ wft,
                                                     float* __restrict__ out)
{
    const int o = blockIdx.x * 256 + threadIdx.x;
    const int g = o >> 9, f = o & 511;
    float s = 0.0f;
#pragma unroll
    for (int ww = 0; ww < 8; ++ww) s += wft[(g * 8 + ww) * 512 + f];
    out[o] = s * 0.125f;
}

// ---------------------------------------------------------------------------
extern "C" void kernel_launch(void* const* d_in, const int* in_sizes, int n_in,
                              void* d_out, int out_size, void* d_ws, size_t ws_size,
                              hipStream_t stream)
{
    const int*   inputs = (const int*)  d_in[0];
    const float* emb    = (const float*)d_in[1];
    const float* w_qkv  = (const float*)d_in[2];
    const float* gam    = (const float*)d_in[3];
    const float* bet    = (const float*)d_in[4];
    const float* w1     = (const float*)d_in[5];
    const float* b1     = (const float*)d_in[6];
    const float* w2     = (const float*)d_in[7];
    const float* b2     = (const float*)d_in[8];
    const float* w3     = (const float*)d_in[9];
    const float* b3     = (const float*)d_in[10];

    float* qkv = (float*)d_ws;                   // 512*1536 f32 = 3MB
    float* sim = qkv + 512 * 1536;               // 512*8*512 f32 = 8MB
    float* wft = sim + 512 * 8 * 512;            // 4096*512 f32 = 8MB
    float* out = (float*)d_out;

    qkv_kernel  <<<dim3(6, 8),    256, 0, stream>>>(emb, w_qkv, qkv);
    sim_kernel  <<<dim3(8, 8, 8), 256, 0, stream>>>(qkv, sim);
    main_kernel <<<4096,          256, 0, stream>>>(inputs, qkv, sim, gam, bet,
                                                    w1, b1, w2, b2, w3, b3, wft);
    reduce_kernel<<<1024,         256, 0, stream>>>(wft, out);
}